// Round 1
// baseline (1484.650 us; speedup 1.0000x reference)
//
#include <hip/hip_runtime.h>

#define N_NODES 50000
#define N_EDGES 800000
#define IN_F    256
#define HIDDEN  128

// ---------------------------------------------------------------------------
// Kernel 1: support = x @ W^T + b     [50000,256] x [128,256]^T -> [50000,128]
// Block: 256 threads. Tile: BM=32 rows x 128 cols (full N), BK=32.
// LDS tiles stored transposed ([kk][row] / [kk][col]) so the inner loop does
// 2x ds_read_b128 per 16 v_fmac (outer-product 4x4 per thread).
// ---------------------------------------------------------------------------
__global__ __launch_bounds__(256) void linear_kernel(
    const float* __restrict__ x, const float* __restrict__ W,
    const float* __restrict__ b, float* __restrict__ support)
{
    // xs stride 36 floats: 144 B row pitch -> 16B-aligned rows, bank rotation 4
    __shared__ __align__(16) float xs[32][36];    // [kk][row]
    __shared__ __align__(16) float ws[32][128];   // [kk][col]

    const int tid = threadIdx.x;
    const int tx  = tid & 31;   // col group (4 cols each)
    const int ty  = tid >> 5;   // row group (4 rows each), 0..7
    const int rowBase = blockIdx.x * 32;

    float acc[4][4];
#pragma unroll
    for (int i = 0; i < 4; ++i)
#pragma unroll
        for (int j = 0; j < 4; ++j) acc[i][j] = 0.f;

    // staging-load index precompute
    const int xr = tid >> 3;          // 0..31  (row within tile)
    const int xc = (tid & 7) * 4;     // 0..28  (k within tile, step 4)
    const int wr = tid >> 1;          // 0..127 (W row = output col)
    const int wk = (tid & 1) * 16;    // 0 or 16 (k within tile, 16-float half)

    int xload_row = rowBase + xr;
    if (xload_row >= N_NODES) xload_row = N_NODES - 1;   // clamp (store guarded)

    for (int k0 = 0; k0 < IN_F; k0 += 32) {
        // ---- stage x tile (32x32) transposed ----
        float4 xv = *(const float4*)(x + (size_t)xload_row * IN_F + k0 + xc);
        xs[xc + 0][xr] = xv.x;
        xs[xc + 1][xr] = xv.y;
        xs[xc + 2][xr] = xv.z;
        xs[xc + 3][xr] = xv.w;

        // ---- stage W tile (128x32) transposed ----
#pragma unroll
        for (int j = 0; j < 4; ++j) {
            float4 wv = *(const float4*)(W + (size_t)wr * IN_F + k0 + wk + 4 * j);
            ws[wk + 4 * j + 0][wr] = wv.x;
            ws[wk + 4 * j + 1][wr] = wv.y;
            ws[wk + 4 * j + 2][wr] = wv.z;
            ws[wk + 4 * j + 3][wr] = wv.w;
        }
        __syncthreads();

#pragma unroll
        for (int kk = 0; kk < 32; ++kk) {
            float4 xf = *(const float4*)(&xs[kk][ty * 4]);
            float4 wf = *(const float4*)(&ws[kk][tx * 4]);
            const float xa[4] = {xf.x, xf.y, xf.z, xf.w};
            const float wa[4] = {wf.x, wf.y, wf.z, wf.w};
#pragma unroll
            for (int i = 0; i < 4; ++i)
#pragma unroll
                for (int j = 0; j < 4; ++j)
                    acc[i][j] += xa[i] * wa[j];
        }
        __syncthreads();
    }

    // bias + store (coalesced float4 per output row)
    const int cbase = tx * 4;
    float4 bias = *(const float4*)(b + cbase);
#pragma unroll
    for (int i = 0; i < 4; ++i) {
        int r = rowBase + ty * 4 + i;
        if (r < N_NODES) {
            float4 o;
            o.x = acc[i][0] + bias.x;
            o.y = acc[i][1] + bias.y;
            o.z = acc[i][2] + bias.z;
            o.w = acc[i][3] + bias.w;
            *(float4*)(support + (size_t)r * HIDDEN + cbase) = o;
        }
    }
}

// ---------------------------------------------------------------------------
// Kernel 2: out[row[e]] += val[e] * support[col[e]]
// One thread per (edge, 4 features): float4 gather + 4 HW fp32 atomics.
// ---------------------------------------------------------------------------
__global__ __launch_bounds__(256) void scatter_kernel(
    const int* __restrict__ adj_row, const int* __restrict__ adj_col,
    const float* __restrict__ adj_val, const float* __restrict__ support,
    float* __restrict__ out)
{
    const int gid = blockIdx.x * 256 + threadIdx.x;
    const int e = gid >> 5;            // edge index
    const int f = (gid & 31) << 2;     // feature offset (0,4,...,124)
    if (e >= N_EDGES) return;

    const int r = adj_row[e];
    const int c = adj_col[e];
    const float v = adj_val[e];

    float4 s = *(const float4*)(support + (size_t)c * HIDDEN + f);
    float* o = out + (size_t)r * HIDDEN + f;
    unsafeAtomicAdd(o + 0, s.x * v);
    unsafeAtomicAdd(o + 1, s.y * v);
    unsafeAtomicAdd(o + 2, s.z * v);
    unsafeAtomicAdd(o + 3, s.w * v);
}

extern "C" void kernel_launch(void* const* d_in, const int* in_sizes, int n_in,
                              void* d_out, int out_size, void* d_ws, size_t ws_size,
                              hipStream_t stream) {
    const float* x       = (const float*)d_in[0];
    const int*   adj_row = (const int*)d_in[1];
    const int*   adj_col = (const int*)d_in[2];
    const float* adj_val = (const float*)d_in[3];
    const float* W       = (const float*)d_in[4];
    const float* b       = (const float*)d_in[5];
    float* out     = (float*)d_out;
    float* support = (float*)d_ws;     // 50000*128*4 = 25.6 MB scratch

    hipMemsetAsync(d_out, 0, (size_t)out_size * sizeof(float), stream);

    linear_kernel<<<(N_NODES + 31) / 32, 256, 0, stream>>>(x, W, b, support);

    const long long scatter_threads = (long long)N_EDGES * 32;
    scatter_kernel<<<(int)((scatter_threads + 255) / 256), 256, 0, stream>>>(
        adj_row, adj_col, adj_val, support, out);
}

// Round 2
// 303.729 us; speedup vs baseline: 4.8881x; 4.8881x over previous
//
#include <hip/hip_runtime.h>

#define N_NODES 50000
#define N_EDGES 800000
#define IN_F    256
#define HIDDEN  128
#define SCAN_B  256

// ---------------------------------------------------------------------------
// Kernel 1: support = x @ W^T + b     [50000,256] x [128,256]^T -> [50000,128]
// ---------------------------------------------------------------------------
__global__ __launch_bounds__(256) void linear_kernel(
    const float* __restrict__ x, const float* __restrict__ W,
    const float* __restrict__ b, float* __restrict__ support)
{
    __shared__ __align__(16) float xs[32][36];    // [kk][row]
    __shared__ __align__(16) float ws[32][128];   // [kk][col]

    const int tid = threadIdx.x;
    const int tx  = tid & 31;   // col group (4 cols each)
    const int ty  = tid >> 5;   // row group (4 rows each), 0..7
    const int rowBase = blockIdx.x * 32;

    float acc[4][4];
#pragma unroll
    for (int i = 0; i < 4; ++i)
#pragma unroll
        for (int j = 0; j < 4; ++j) acc[i][j] = 0.f;

    const int xr = tid >> 3;          // 0..31
    const int xc = (tid & 7) * 4;     // 0..28
    const int wr = tid >> 1;          // 0..127
    const int wk = (tid & 1) * 16;    // 0 or 16

    int xload_row = rowBase + xr;
    if (xload_row >= N_NODES) xload_row = N_NODES - 1;

    for (int k0 = 0; k0 < IN_F; k0 += 32) {
        float4 xv = *(const float4*)(x + (size_t)xload_row * IN_F + k0 + xc);
        xs[xc + 0][xr] = xv.x;
        xs[xc + 1][xr] = xv.y;
        xs[xc + 2][xr] = xv.z;
        xs[xc + 3][xr] = xv.w;

#pragma unroll
        for (int j = 0; j < 4; ++j) {
            float4 wv = *(const float4*)(W + (size_t)wr * IN_F + k0 + wk + 4 * j);
            ws[wk + 4 * j + 0][wr] = wv.x;
            ws[wk + 4 * j + 1][wr] = wv.y;
            ws[wk + 4 * j + 2][wr] = wv.z;
            ws[wk + 4 * j + 3][wr] = wv.w;
        }
        __syncthreads();

#pragma unroll
        for (int kk = 0; kk < 32; ++kk) {
            float4 xf = *(const float4*)(&xs[kk][ty * 4]);
            float4 wf = *(const float4*)(&ws[kk][tx * 4]);
            const float xa[4] = {xf.x, xf.y, xf.z, xf.w};
            const float wa[4] = {wf.x, wf.y, wf.z, wf.w};
#pragma unroll
            for (int i = 0; i < 4; ++i)
#pragma unroll
                for (int j = 0; j < 4; ++j)
                    acc[i][j] += xa[i] * wa[j];
        }
        __syncthreads();
    }

    const int cbase = tx * 4;
    float4 bias = *(const float4*)(b + cbase);
#pragma unroll
    for (int i = 0; i < 4; ++i) {
        int r = rowBase + ty * 4 + i;
        if (r < N_NODES) {
            float4 o;
            o.x = acc[i][0] + bias.x;
            o.y = acc[i][1] + bias.y;
            o.z = acc[i][2] + bias.z;
            o.w = acc[i][3] + bias.w;
            *(float4*)(support + (size_t)r * HIDDEN + cbase) = o;
        }
    }
}

// ---------------------------------------------------------------------------
// CSR build: histogram -> scan -> bucket fill
// ---------------------------------------------------------------------------
__global__ __launch_bounds__(256) void hist_kernel(
    const int* __restrict__ adj_row, int* __restrict__ counts)
{
    int e = blockIdx.x * 256 + threadIdx.x;
    if (e < N_EDGES) atomicAdd(&counts[adj_row[e]], 1);
}

__global__ __launch_bounds__(SCAN_B) void block_sum_kernel(
    const int* __restrict__ counts, int* __restrict__ blockSums)
{
    __shared__ int s[SCAN_B];
    int i = blockIdx.x * SCAN_B + threadIdx.x;
    s[threadIdx.x] = (i < N_NODES) ? counts[i] : 0;
    __syncthreads();
#pragma unroll
    for (int off = SCAN_B / 2; off > 0; off >>= 1) {
        if (threadIdx.x < off) s[threadIdx.x] += s[threadIdx.x + off];
        __syncthreads();
    }
    if (threadIdx.x == 0) blockSums[blockIdx.x] = s[0];
}

__global__ __launch_bounds__(SCAN_B) void scan_block_sums_kernel(
    int* __restrict__ blockSums, int n)
{
    __shared__ int s[SCAN_B];
    s[threadIdx.x] = (threadIdx.x < n) ? blockSums[threadIdx.x] : 0;
    __syncthreads();
    if (threadIdx.x == 0) {
        int run = 0;
        for (int i = 0; i < n; ++i) { int t = s[i]; s[i] = run; run += t; }
    }
    __syncthreads();
    if (threadIdx.x < n) blockSums[threadIdx.x] = s[threadIdx.x];
}

__global__ __launch_bounds__(SCAN_B) void scan_final_kernel(
    const int* __restrict__ counts, const int* __restrict__ blockSums,
    int* __restrict__ row_ptr)
{
    __shared__ int s[SCAN_B];
    int i = blockIdx.x * SCAN_B + threadIdx.x;
    int v = (i < N_NODES) ? counts[i] : 0;
    s[threadIdx.x] = v;
    __syncthreads();
#pragma unroll
    for (int off = 1; off < SCAN_B; off <<= 1) {
        int t = (threadIdx.x >= off) ? s[threadIdx.x - off] : 0;
        __syncthreads();
        s[threadIdx.x] += t;
        __syncthreads();
    }
    int incl = s[threadIdx.x];
    int base = blockSums[blockIdx.x];
    if (i < N_NODES) row_ptr[i] = base + incl - v;
    if (i == N_NODES - 1) row_ptr[N_NODES] = base + incl;
}

__global__ __launch_bounds__(256) void fill_csr_kernel(
    const int* __restrict__ adj_row, const int* __restrict__ adj_col,
    const float* __restrict__ adj_val, const int* __restrict__ row_ptr,
    int* __restrict__ cursor, int* __restrict__ csr_col,
    float* __restrict__ csr_val)
{
    int e = blockIdx.x * 256 + threadIdx.x;
    if (e >= N_EDGES) return;
    int r = adj_row[e];
    int pos = row_ptr[r] + atomicAdd(&cursor[r], 1);
    csr_col[pos] = adj_col[e];
    csr_val[pos] = adj_val[e];
}

// ---------------------------------------------------------------------------
// Gather: one 128-thread block per output row, thread = feature.
// Per edge: coalesced 512 B read of support[col], register accumulate.
// ---------------------------------------------------------------------------
__global__ __launch_bounds__(128) void gather_kernel(
    const int* __restrict__ row_ptr, const int* __restrict__ csr_col,
    const float* __restrict__ csr_val, const float* __restrict__ support,
    float* __restrict__ out)
{
    const int r = blockIdx.x;
    const int f = threadIdx.x;
    int s = row_ptr[r], e = row_ptr[r + 1];
    float acc = 0.f;
    int i = s;
    for (; i + 1 < e; i += 2) {
        int   c0 = csr_col[i],   c1 = csr_col[i + 1];
        float v0 = csr_val[i],   v1 = csr_val[i + 1];
        float s0 = support[(size_t)c0 * HIDDEN + f];
        float s1 = support[(size_t)c1 * HIDDEN + f];
        acc += v0 * s0;
        acc += v1 * s1;
    }
    if (i < e)
        acc += csr_val[i] * support[(size_t)csr_col[i] * HIDDEN + f];
    out[(size_t)r * HIDDEN + f] = acc;
}

// ---------------------------------------------------------------------------
// Fallback scatter (atomics) if workspace too small for CSR path.
// ---------------------------------------------------------------------------
__global__ __launch_bounds__(256) void scatter_kernel(
    const int* __restrict__ adj_row, const int* __restrict__ adj_col,
    const float* __restrict__ adj_val, const float* __restrict__ support,
    float* __restrict__ out)
{
    const int gid = blockIdx.x * 256 + threadIdx.x;
    const int e = gid >> 5;
    const int f = (gid & 31) << 2;
    if (e >= N_EDGES) return;
    const int r = adj_row[e];
    const int c = adj_col[e];
    const float v = adj_val[e];
    float4 s = *(const float4*)(support + (size_t)c * HIDDEN + f);
    float* o = out + (size_t)r * HIDDEN + f;
    unsafeAtomicAdd(o + 0, s.x * v);
    unsafeAtomicAdd(o + 1, s.y * v);
    unsafeAtomicAdd(o + 2, s.z * v);
    unsafeAtomicAdd(o + 3, s.w * v);
}

extern "C" void kernel_launch(void* const* d_in, const int* in_sizes, int n_in,
                              void* d_out, int out_size, void* d_ws, size_t ws_size,
                              hipStream_t stream) {
    const float* x       = (const float*)d_in[0];
    const int*   adj_row = (const int*)d_in[1];
    const int*   adj_col = (const int*)d_in[2];
    const float* adj_val = (const float*)d_in[3];
    const float* W       = (const float*)d_in[4];
    const float* b       = (const float*)d_in[5];
    float* out = (float*)d_out;

    char* wsb = (char*)d_ws;
    // workspace layout
    const size_t off_support = 0;                                  // 25.6 MB
    const size_t off_counts  = off_support + (size_t)N_NODES * HIDDEN * 4;
    const size_t off_rowptr  = off_counts + (size_t)N_NODES * 4;
    const size_t off_cursor  = off_rowptr + (size_t)(N_NODES + 1) * 4 + 12; // keep 16B align
    const size_t off_csrcol  = off_cursor + (size_t)N_NODES * 4;
    const size_t off_csrval  = off_csrcol + (size_t)N_EDGES * 4;
    const size_t off_bsums   = off_csrval + (size_t)N_EDGES * 4;
    const int    nScanBlocks = (N_NODES + SCAN_B - 1) / SCAN_B;    // 196
    const size_t ws_needed   = off_bsums + (size_t)nScanBlocks * 4;

    float* support = (float*)(wsb + off_support);

    // support = x @ W^T + b (common to both paths)
    linear_kernel<<<(N_NODES + 31) / 32, 256, 0, stream>>>(x, W, b, support);

    if (ws_size >= ws_needed) {
        int*   counts  = (int*)(wsb + off_counts);
        int*   row_ptr = (int*)(wsb + off_rowptr);
        int*   cursor  = (int*)(wsb + off_cursor);
        int*   csr_col = (int*)(wsb + off_csrcol);
        float* csr_val = (float*)(wsb + off_csrval);
        int*   bsums   = (int*)(wsb + off_bsums);

        hipMemsetAsync(counts, 0, (size_t)N_NODES * 4, stream);
        hipMemsetAsync(cursor, 0, (size_t)N_NODES * 4, stream);

        hist_kernel<<<(N_EDGES + 255) / 256, 256, 0, stream>>>(adj_row, counts);
        block_sum_kernel<<<nScanBlocks, SCAN_B, 0, stream>>>(counts, bsums);
        scan_block_sums_kernel<<<1, SCAN_B, 0, stream>>>(bsums, nScanBlocks);
        scan_final_kernel<<<nScanBlocks, SCAN_B, 0, stream>>>(counts, bsums, row_ptr);
        fill_csr_kernel<<<(N_EDGES + 255) / 256, 256, 0, stream>>>(
            adj_row, adj_col, adj_val, row_ptr, cursor, csr_col, csr_val);
        gather_kernel<<<N_NODES, 128, 0, stream>>>(
            row_ptr, csr_col, csr_val, support, out);
    } else {
        // fallback: atomic scatter
        hipMemsetAsync(d_out, 0, (size_t)out_size * sizeof(float), stream);
        const long long scatter_threads = (long long)N_EDGES * 32;
        scatter_kernel<<<(int)((scatter_threads + 255) / 256), 256, 0, stream>>>(
            adj_row, adj_col, adj_val, support, out);
    }
}

// Round 3
// 298.943 us; speedup vs baseline: 4.9663x; 1.0160x over previous
//
#include <hip/hip_runtime.h>

#define N_NODES 50000
#define N_EDGES 800000
#define IN_F    256
#define HIDDEN  128
#define SCAN_B  256

typedef __attribute__((ext_vector_type(8))) short bf16x8;
typedef __attribute__((ext_vector_type(4))) float f32x4;

__device__ inline unsigned short f2bf(float f) {
    unsigned u = __float_as_uint(f);
    u += 0x7FFF + ((u >> 16) & 1);          // round-to-nearest-even
    return (unsigned short)(u >> 16);
}
__device__ inline bf16x8 cvt8(float4 a, float4 b) {
    bf16x8 r;
    r[0] = (short)f2bf(a.x); r[1] = (short)f2bf(a.y);
    r[2] = (short)f2bf(a.z); r[3] = (short)f2bf(a.w);
    r[4] = (short)f2bf(b.x); r[5] = (short)f2bf(b.y);
    r[6] = (short)f2bf(b.z); r[7] = (short)f2bf(b.w);
    return r;
}

// ---------------------------------------------------------------------------
// Linear via MFMA bf16: support_bf16 = bf16(x @ W^T + b).
// Block 256 thr = 4 waves; wave handles M=16 rows x N=128 (8 strips of 16).
// Fragments are k-contiguous -> direct global loads, no LDS.
// A-frag: A[m=lane&15][k=quad*8+j]; B-frag: B[k=quad*8+j][n=lane&15]=W[n][k].
// C/D: col=lane&15, row=quad*4+reg  (verified layout, m89/m91).
// ---------------------------------------------------------------------------
__global__ __launch_bounds__(256) void linear_mfma_kernel(
    const float* __restrict__ x, const float* __restrict__ W,
    const float* __restrict__ bias, unsigned short* __restrict__ support)
{
    const int lane = threadIdx.x & 63;
    const int wave = threadIdx.x >> 6;
    const int quad = lane >> 4;
    const int l16  = lane & 15;

    int m = blockIdx.x * 64 + wave * 16 + l16;
    if (m >= N_NODES) m = N_NODES - 1;            // clamp (stores guarded)
    const float* xrow = x + (size_t)m * IN_F;

    f32x4 acc[8];
#pragma unroll
    for (int s = 0; s < 8; ++s) acc[s] = (f32x4){0.f, 0.f, 0.f, 0.f};

#pragma unroll
    for (int kc = 0; kc < 8; ++kc) {
        const int k0 = kc * 32 + quad * 8;
        float4 a0 = *(const float4*)(xrow + k0);
        float4 a1 = *(const float4*)(xrow + k0 + 4);
        bf16x8 af = cvt8(a0, a1);
#pragma unroll
        for (int s = 0; s < 8; ++s) {
            const float* wrow = W + (size_t)(s * 16 + l16) * IN_F + k0;
            float4 b0 = *(const float4*)(wrow);
            float4 b1 = *(const float4*)(wrow + 4);
            bf16x8 bf = cvt8(b0, b1);
            acc[s] = __builtin_amdgcn_mfma_f32_16x16x32_bf16(af, bf, acc[s], 0, 0, 0);
        }
    }

    const int rowBase = blockIdx.x * 64 + wave * 16 + quad * 4;
#pragma unroll
    for (int reg = 0; reg < 4; ++reg) {
        const int r = rowBase + reg;
        if (r < N_NODES) {
#pragma unroll
            for (int s = 0; s < 8; ++s) {
                const int col = s * 16 + l16;
                float v = acc[s][reg] + bias[col];
                support[(size_t)r * HIDDEN + col] = f2bf(v);
            }
        }
    }
}

// ---------------------------------------------------------------------------
// CSR build: histogram -> scan -> bucket fill (int2-packed, atomicSub cursor)
// ---------------------------------------------------------------------------
__global__ __launch_bounds__(256) void hist_kernel(
    const int* __restrict__ adj_row, int* __restrict__ counts)
{
    int e = blockIdx.x * 256 + threadIdx.x;
    if (e < N_EDGES) atomicAdd(&counts[adj_row[e]], 1);
}

__global__ __launch_bounds__(SCAN_B) void block_sum_kernel(
    const int* __restrict__ counts, int* __restrict__ blockSums)
{
    __shared__ int s[SCAN_B];
    int i = blockIdx.x * SCAN_B + threadIdx.x;
    s[threadIdx.x] = (i < N_NODES) ? counts[i] : 0;
    __syncthreads();
#pragma unroll
    for (int off = SCAN_B / 2; off > 0; off >>= 1) {
        if (threadIdx.x < off) s[threadIdx.x] += s[threadIdx.x + off];
        __syncthreads();
    }
    if (threadIdx.x == 0) blockSums[blockIdx.x] = s[0];
}

// exclusive scan of up to 256 block sums (parallel Hillis-Steele)
__global__ __launch_bounds__(SCAN_B) void scan_block_sums_kernel(
    int* __restrict__ blockSums, int n)
{
    __shared__ int s[SCAN_B];
    int v = (threadIdx.x < n) ? blockSums[threadIdx.x] : 0;
    s[threadIdx.x] = v;
    __syncthreads();
#pragma unroll
    for (int off = 1; off < SCAN_B; off <<= 1) {
        int t = (threadIdx.x >= off) ? s[threadIdx.x - off] : 0;
        __syncthreads();
        s[threadIdx.x] += t;
        __syncthreads();
    }
    if (threadIdx.x < n) blockSums[threadIdx.x] = s[threadIdx.x] - v;  // exclusive
}

__global__ __launch_bounds__(SCAN_B) void scan_final_kernel(
    const int* __restrict__ counts, const int* __restrict__ blockSums,
    int* __restrict__ row_ptr)
{
    __shared__ int s[SCAN_B];
    int i = blockIdx.x * SCAN_B + threadIdx.x;
    int v = (i < N_NODES) ? counts[i] : 0;
    s[threadIdx.x] = v;
    __syncthreads();
#pragma unroll
    for (int off = 1; off < SCAN_B; off <<= 1) {
        int t = (threadIdx.x >= off) ? s[threadIdx.x - off] : 0;
        __syncthreads();
        s[threadIdx.x] += t;
        __syncthreads();
    }
    int incl = s[threadIdx.x];
    int base = blockSums[blockIdx.x];
    if (i < N_NODES) row_ptr[i] = base + incl - v;
    if (i == N_NODES - 1) row_ptr[N_NODES] = base + incl;
}

// counts doubles as the cursor: atomicSub gives a unique slot per edge.
__global__ __launch_bounds__(256) void fill_csr_kernel(
    const int* __restrict__ adj_row, const int* __restrict__ adj_col,
    const float* __restrict__ adj_val, const int* __restrict__ row_ptr,
    int* __restrict__ counts, int2* __restrict__ csr_cv)
{
    int e = blockIdx.x * 256 + threadIdx.x;
    if (e >= N_EDGES) return;
    int r = adj_row[e];
    int pos = row_ptr[r] + atomicSub(&counts[r], 1) - 1;
    csr_cv[pos] = make_int2(adj_col[e], __float_as_int(adj_val[e]));
}

// ---------------------------------------------------------------------------
// Gather: wave-per-row (4 rows / 256-thr block); lane handles 2 features via
// one uint (2x bf16) load -> 256 B coalesced per edge; fp32 accumulate.
// ---------------------------------------------------------------------------
__global__ __launch_bounds__(256) void gather_kernel(
    const int* __restrict__ row_ptr, const int2* __restrict__ csr_cv,
    const unsigned int* __restrict__ support_u32, float* __restrict__ out)
{
    const int wave = threadIdx.x >> 6;
    const int lane = threadIdx.x & 63;
    const int r = blockIdx.x * 4 + wave;
    if (r >= N_NODES) return;

    const int s = row_ptr[r], e = row_ptr[r + 1];
    float accx = 0.f, accy = 0.f;
    int i = s;
    for (; i + 1 < e; i += 2) {
        int2 cv0 = csr_cv[i];
        int2 cv1 = csr_cv[i + 1];
        unsigned u0 = support_u32[(size_t)cv0.x * 64 + lane];
        unsigned u1 = support_u32[(size_t)cv1.x * 64 + lane];
        float v0 = __int_as_float(cv0.y);
        float v1 = __int_as_float(cv1.y);
        accx += v0 * __uint_as_float(u0 << 16);
        accy += v0 * __uint_as_float(u0 & 0xFFFF0000u);
        accx += v1 * __uint_as_float(u1 << 16);
        accy += v1 * __uint_as_float(u1 & 0xFFFF0000u);
    }
    if (i < e) {
        int2 cv = csr_cv[i];
        unsigned u = support_u32[(size_t)cv.x * 64 + lane];
        float v = __int_as_float(cv.y);
        accx += v * __uint_as_float(u << 16);
        accy += v * __uint_as_float(u & 0xFFFF0000u);
    }
    float2 o = make_float2(accx, accy);
    *(float2*)(out + (size_t)r * HIDDEN + lane * 2) = o;
}

extern "C" void kernel_launch(void* const* d_in, const int* in_sizes, int n_in,
                              void* d_out, int out_size, void* d_ws, size_t ws_size,
                              hipStream_t stream) {
    const float* x       = (const float*)d_in[0];
    const int*   adj_row = (const int*)d_in[1];
    const int*   adj_col = (const int*)d_in[2];
    const float* adj_val = (const float*)d_in[3];
    const float* W       = (const float*)d_in[4];
    const float* b       = (const float*)d_in[5];
    float* out = (float*)d_out;

    char* wsb = (char*)d_ws;
    const size_t off_support = 0;                                        // 12.8 MB (bf16)
    const size_t off_counts  = off_support + (size_t)N_NODES * HIDDEN * 2;
    const size_t off_rowptr  = off_counts + (size_t)N_NODES * 4;
    const size_t off_csrcv   = (off_rowptr + (size_t)(N_NODES + 1) * 4 + 15) & ~(size_t)15;
    const size_t off_bsums   = off_csrcv + (size_t)N_EDGES * 8;          // 6.4 MB
    const int    nScanBlocks = (N_NODES + SCAN_B - 1) / SCAN_B;          // 196

    unsigned short* support = (unsigned short*)(wsb + off_support);
    int*   counts  = (int*)(wsb + off_counts);
    int*   row_ptr = (int*)(wsb + off_rowptr);
    int2*  csr_cv  = (int2*)(wsb + off_csrcv);
    int*   bsums   = (int*)(wsb + off_bsums);

    hipMemsetAsync(counts, 0, (size_t)N_NODES * 4, stream);

    linear_mfma_kernel<<<(N_NODES + 63) / 64, 256, 0, stream>>>(x, W, b, support);

    hist_kernel<<<(N_EDGES + 255) / 256, 256, 0, stream>>>(adj_row, counts);
    block_sum_kernel<<<nScanBlocks, SCAN_B, 0, stream>>>(counts, bsums);
    scan_block_sums_kernel<<<1, SCAN_B, 0, stream>>>(bsums, nScanBlocks);
    scan_final_kernel<<<nScanBlocks, SCAN_B, 0, stream>>>(counts, bsums, row_ptr);
    fill_csr_kernel<<<(N_EDGES + 255) / 256, 256, 0, stream>>>(
        adj_row, adj_col, adj_val, row_ptr, counts, csr_cv);
    gather_kernel<<<(N_NODES + 3) / 4, 256, 0, stream>>>(
        row_ptr, csr_cv, (const unsigned int*)support, out);
}

// Round 4
// 246.740 us; speedup vs baseline: 6.0171x; 1.2116x over previous
//
#include <hip/hip_runtime.h>

#define N_NODES 50000
#define N_EDGES 800000
#define IN_F    256
#define HIDDEN  128
#define SCAN_B  256

typedef __attribute__((ext_vector_type(8))) short bf16x8;
typedef __attribute__((ext_vector_type(4))) float f32x4;

__device__ inline unsigned short f2bf(float f) {
    unsigned u = __float_as_uint(f);
    u += 0x7FFF + ((u >> 16) & 1);          // round-to-nearest-even
    return (unsigned short)(u >> 16);
}
__device__ inline bf16x8 cvt8(float4 a, float4 b) {
    bf16x8 r;
    r[0] = (short)f2bf(a.x); r[1] = (short)f2bf(a.y);
    r[2] = (short)f2bf(a.z); r[3] = (short)f2bf(a.w);
    r[4] = (short)f2bf(b.x); r[5] = (short)f2bf(b.y);
    r[6] = (short)f2bf(b.z); r[7] = (short)f2bf(b.w);
    return r;
}

// ---------------------------------------------------------------------------
// Linear via MFMA bf16: support_bf16 = bf16(x @ W^T + b).
// W staged ONCE per block in LDS, pre-swizzled into B-fragment order:
//   wfrag[kc][s][lane] = 8 bf16 = W[s*16 + (lane&15)][kc*32 + (lane>>4)*8 ..+7]
// Compute reads are lane-contiguous 16 B (ds_read_b128, conflict-free).
// Block 256 thr = 4 waves; wave handles M=16 rows x N=128 (8 strips).
// A-frag: A[m=lane&15][k=quad*8+j]; C/D: col=lane&15, row=quad*4+reg.
// ---------------------------------------------------------------------------
__global__ __launch_bounds__(256) void linear_mfma_kernel(
    const float* __restrict__ x, const float* __restrict__ W,
    const float* __restrict__ bias, unsigned short* __restrict__ support)
{
    __shared__ __align__(16) short wfrag[8 * 8 * 64 * 8];   // 64 KB

    const int tid = threadIdx.x;

    // ---- stage W fragments (4096 frags of 16 B, 16 per thread) ----
#pragma unroll
    for (int it = 0; it < 16; ++it) {
        const int f    = it * 256 + tid;
        const int ln   = f & 63;
        const int s    = (f >> 6) & 7;
        const int kc   = f >> 9;
        const int row  = s * 16 + (ln & 15);
        const int k0   = kc * 32 + (ln >> 4) * 8;
        const float* wp = W + (size_t)row * IN_F + k0;
        float4 b0 = *(const float4*)wp;
        float4 b1 = *(const float4*)(wp + 4);
        *(bf16x8*)(&wfrag[(size_t)f * 8]) = cvt8(b0, b1);
    }
    __syncthreads();

    const int lane = tid & 63;
    const int wave = tid >> 6;
    const int quad = lane >> 4;
    const int l16  = lane & 15;

    int m = blockIdx.x * 64 + wave * 16 + l16;
    if (m >= N_NODES) m = N_NODES - 1;            // clamp (stores guarded)
    const float* xrow = x + (size_t)m * IN_F;

    f32x4 acc[8];
#pragma unroll
    for (int s = 0; s < 8; ++s) acc[s] = (f32x4){0.f, 0.f, 0.f, 0.f};

#pragma unroll
    for (int kc = 0; kc < 8; ++kc) {
        const int k0 = kc * 32 + quad * 8;
        float4 a0 = *(const float4*)(xrow + k0);
        float4 a1 = *(const float4*)(xrow + k0 + 4);
        bf16x8 af = cvt8(a0, a1);
        const short* bbase = &wfrag[((size_t)(kc * 8) * 64 + lane) * 8];
#pragma unroll
        for (int s = 0; s < 8; ++s) {
            bf16x8 bf = *(const bf16x8*)(bbase + (size_t)s * 64 * 8);
            acc[s] = __builtin_amdgcn_mfma_f32_16x16x32_bf16(af, bf, acc[s], 0, 0, 0);
        }
    }

    const int rowBase = blockIdx.x * 64 + wave * 16 + quad * 4;
#pragma unroll
    for (int reg = 0; reg < 4; ++reg) {
        const int r = rowBase + reg;
        if (r < N_NODES) {
#pragma unroll
            for (int s = 0; s < 8; ++s) {
                const int col = s * 16 + l16;
                float v = acc[s][reg] + bias[col];
                support[(size_t)r * HIDDEN + col] = f2bf(v);
            }
        }
    }
}

// ---------------------------------------------------------------------------
// CSR build: histogram -> scan -> bucket fill (int2-packed, atomicSub cursor)
// ---------------------------------------------------------------------------
__global__ __launch_bounds__(256) void hist_kernel(
    const int* __restrict__ adj_row, int* __restrict__ counts)
{
    int e = blockIdx.x * 256 + threadIdx.x;
    if (e < N_EDGES) atomicAdd(&counts[adj_row[e]], 1);
}

__global__ __launch_bounds__(SCAN_B) void block_sum_kernel(
    const int* __restrict__ counts, int* __restrict__ blockSums)
{
    __shared__ int s[SCAN_B];
    int i = blockIdx.x * SCAN_B + threadIdx.x;
    s[threadIdx.x] = (i < N_NODES) ? counts[i] : 0;
    __syncthreads();
#pragma unroll
    for (int off = SCAN_B / 2; off > 0; off >>= 1) {
        if (threadIdx.x < off) s[threadIdx.x] += s[threadIdx.x + off];
        __syncthreads();
    }
    if (threadIdx.x == 0) blockSums[blockIdx.x] = s[0];
}

// exclusive scan of up to 256 block sums
__global__ __launch_bounds__(SCAN_B) void scan_block_sums_kernel(
    int* __restrict__ blockSums, int n)
{
    __shared__ int s[SCAN_B];
    int v = (threadIdx.x < n) ? blockSums[threadIdx.x] : 0;
    s[threadIdx.x] = v;
    __syncthreads();
#pragma unroll
    for (int off = 1; off < SCAN_B; off <<= 1) {
        int t = (threadIdx.x >= off) ? s[threadIdx.x - off] : 0;
        __syncthreads();
        s[threadIdx.x] += t;
        __syncthreads();
    }
    if (threadIdx.x < n) blockSums[threadIdx.x] = s[threadIdx.x] - v;  // exclusive
}

__global__ __launch_bounds__(SCAN_B) void scan_final_kernel(
    const int* __restrict__ counts, const int* __restrict__ blockSums,
    int* __restrict__ row_ptr)
{
    __shared__ int s[SCAN_B];
    int i = blockIdx.x * SCAN_B + threadIdx.x;
    int v = (i < N_NODES) ? counts[i] : 0;
    s[threadIdx.x] = v;
    __syncthreads();
#pragma unroll
    for (int off = 1; off < SCAN_B; off <<= 1) {
        int t = (threadIdx.x >= off) ? s[threadIdx.x - off] : 0;
        __syncthreads();
        s[threadIdx.x] += t;
        __syncthreads();
    }
    int incl = s[threadIdx.x];
    int base = blockSums[blockIdx.x];
    if (i < N_NODES) row_ptr[i] = base + incl - v;
    if (i == N_NODES - 1) row_ptr[N_NODES] = base + incl;
}

// counts doubles as the cursor: atomicSub gives a unique slot per edge.
__global__ __launch_bounds__(256) void fill_csr_kernel(
    const int* __restrict__ adj_row, const int* __restrict__ adj_col,
    const float* __restrict__ adj_val, const int* __restrict__ row_ptr,
    int* __restrict__ counts, int2* __restrict__ csr_cv)
{
    int e = blockIdx.x * 256 + threadIdx.x;
    if (e >= N_EDGES) return;
    int r = adj_row[e];
    int pos = row_ptr[r] + atomicSub(&counts[r], 1) - 1;
    csr_cv[pos] = make_int2(adj_col[e], __float_as_int(adj_val[e]));
}

// ---------------------------------------------------------------------------
// Gather: wave-per-row (4 rows / 256-thr block); lane handles 2 features via
// one uint (2x bf16) load -> 256 B coalesced per edge; fp32 accumulate.
// Unroll 4 with hoisted edge-entry loads for latency hiding.
// ---------------------------------------------------------------------------
__global__ __launch_bounds__(256) void gather_kernel(
    const int* __restrict__ row_ptr, const int2* __restrict__ csr_cv,
    const unsigned int* __restrict__ support_u32, float* __restrict__ out)
{
    const int wave = threadIdx.x >> 6;
    const int lane = threadIdx.x & 63;
    const int r = blockIdx.x * 4 + wave;
    if (r >= N_NODES) return;

    const int s = row_ptr[r], e = row_ptr[r + 1];
    float accx = 0.f, accy = 0.f;
    int i = s;
    for (; i + 3 < e; i += 4) {
        int2 cv0 = csr_cv[i];
        int2 cv1 = csr_cv[i + 1];
        int2 cv2 = csr_cv[i + 2];
        int2 cv3 = csr_cv[i + 3];
        unsigned u0 = support_u32[(size_t)cv0.x * 64 + lane];
        unsigned u1 = support_u32[(size_t)cv1.x * 64 + lane];
        unsigned u2 = support_u32[(size_t)cv2.x * 64 + lane];
        unsigned u3 = support_u32[(size_t)cv3.x * 64 + lane];
        float v0 = __int_as_float(cv0.y), v1 = __int_as_float(cv1.y);
        float v2 = __int_as_float(cv2.y), v3 = __int_as_float(cv3.y);
        accx += v0 * __uint_as_float(u0 << 16);
        accy += v0 * __uint_as_float(u0 & 0xFFFF0000u);
        accx += v1 * __uint_as_float(u1 << 16);
        accy += v1 * __uint_as_float(u1 & 0xFFFF0000u);
        accx += v2 * __uint_as_float(u2 << 16);
        accy += v2 * __uint_as_float(u2 & 0xFFFF0000u);
        accx += v3 * __uint_as_float(u3 << 16);
        accy += v3 * __uint_as_float(u3 & 0xFFFF0000u);
    }
    for (; i < e; ++i) {
        int2 cv = csr_cv[i];
        unsigned u = support_u32[(size_t)cv.x * 64 + lane];
        float v = __int_as_float(cv.y);
        accx += v * __uint_as_float(u << 16);
        accy += v * __uint_as_float(u & 0xFFFF0000u);
    }
    *(float2*)(out + (size_t)r * HIDDEN + lane * 2) = make_float2(accx, accy);
}

extern "C" void kernel_launch(void* const* d_in, const int* in_sizes, int n_in,
                              void* d_out, int out_size, void* d_ws, size_t ws_size,
                              hipStream_t stream) {
    const float* x       = (const float*)d_in[0];
    const int*   adj_row = (const int*)d_in[1];
    const int*   adj_col = (const int*)d_in[2];
    const float* adj_val = (const float*)d_in[3];
    const float* W       = (const float*)d_in[4];
    const float* b       = (const float*)d_in[5];
    float* out = (float*)d_out;

    char* wsb = (char*)d_ws;
    const size_t off_support = 0;                                        // 12.8 MB (bf16)
    const size_t off_counts  = off_support + (size_t)N_NODES * HIDDEN * 2;
    const size_t off_rowptr  = off_counts + (size_t)N_NODES * 4;
    const size_t off_csrcv   = (off_rowptr + (size_t)(N_NODES + 1) * 4 + 15) & ~(size_t)15;
    const size_t off_bsums   = off_csrcv + (size_t)N_EDGES * 8;          // 6.4 MB
    const int    nScanBlocks = (N_NODES + SCAN_B - 1) / SCAN_B;          // 196

    unsigned short* support = (unsigned short*)(wsb + off_support);
    int*   counts  = (int*)(wsb + off_counts);
    int*   row_ptr = (int*)(wsb + off_rowptr);
    int2*  csr_cv  = (int2*)(wsb + off_csrcv);
    int*   bsums   = (int*)(wsb + off_bsums);

    hipMemsetAsync(counts, 0, (size_t)N_NODES * 4, stream);

    linear_mfma_kernel<<<(N_NODES + 63) / 64, 256, 0, stream>>>(x, W, b, support);

    hist_kernel<<<(N_EDGES + 255) / 256, 256, 0, stream>>>(adj_row, counts);
    block_sum_kernel<<<nScanBlocks, SCAN_B, 0, stream>>>(counts, bsums);
    scan_block_sums_kernel<<<1, SCAN_B, 0, stream>>>(bsums, nScanBlocks);
    scan_final_kernel<<<nScanBlocks, SCAN_B, 0, stream>>>(counts, bsums, row_ptr);
    fill_csr_kernel<<<(N_EDGES + 255) / 256, 256, 0, stream>>>(
        adj_row, adj_col, adj_val, row_ptr, counts, csr_cv);
    gather_kernel<<<(N_NODES + 3) / 4, 256, 0, stream>>>(
        row_ptr, csr_cv, (const unsigned int*)support, out);
}

// Round 5
// 209.240 us; speedup vs baseline: 7.0954x; 1.1792x over previous
//
#include <hip/hip_runtime.h>

#define N_NODES 50000
#define N_EDGES 800000
#define IN_F    256
#define HIDDEN  128

#define BUCKET_SZ 128                         // rows per bucket
#define NB        391                         // ceil(N_NODES / BUCKET_SZ)
#define EBLOCK    4096                        // edges per partition block
#define EBLOCKS   196                         // ceil(N_EDGES / EBLOCK)
#define D_CAP     3072                        // LDS staging cap in pass D (mean 2048, sigma~45)

typedef __attribute__((ext_vector_type(8))) short bf16x8;
typedef __attribute__((ext_vector_type(4))) float f32x4;

__device__ inline unsigned short f2bf(float f) {
    unsigned u = __float_as_uint(f);
    u += 0x7FFF + ((u >> 16) & 1);          // round-to-nearest-even
    return (unsigned short)(u >> 16);
}
__device__ inline bf16x8 cvt8(float4 a, float4 b) {
    bf16x8 r;
    r[0] = (short)f2bf(a.x); r[1] = (short)f2bf(a.y);
    r[2] = (short)f2bf(a.z); r[3] = (short)f2bf(a.w);
    r[4] = (short)f2bf(b.x); r[5] = (short)f2bf(b.y);
    r[6] = (short)f2bf(b.z); r[7] = (short)f2bf(b.w);
    return r;
}

// ---------------------------------------------------------------------------
// Linear via MFMA bf16 (unchanged from R4): W staged once per block in LDS,
// pre-swizzled into B-fragment order; A-frags via coalesced global loads.
// ---------------------------------------------------------------------------
__global__ __launch_bounds__(256) void linear_mfma_kernel(
    const float* __restrict__ x, const float* __restrict__ W,
    const float* __restrict__ bias, unsigned short* __restrict__ support)
{
    __shared__ __align__(16) short wfrag[8 * 8 * 64 * 8];   // 64 KB

    const int tid = threadIdx.x;
#pragma unroll
    for (int it = 0; it < 16; ++it) {
        const int f    = it * 256 + tid;
        const int ln   = f & 63;
        const int s    = (f >> 6) & 7;
        const int kc   = f >> 9;
        const int row  = s * 16 + (ln & 15);
        const int k0   = kc * 32 + (ln >> 4) * 8;
        const float* wp = W + (size_t)row * IN_F + k0;
        float4 b0 = *(const float4*)wp;
        float4 b1 = *(const float4*)(wp + 4);
        *(bf16x8*)(&wfrag[(size_t)f * 8]) = cvt8(b0, b1);
    }
    __syncthreads();

    const int lane = tid & 63;
    const int wave = tid >> 6;
    const int quad = lane >> 4;
    const int l16  = lane & 15;

    int m = blockIdx.x * 64 + wave * 16 + l16;
    if (m >= N_NODES) m = N_NODES - 1;
    const float* xrow = x + (size_t)m * IN_F;

    f32x4 acc[8];
#pragma unroll
    for (int s = 0; s < 8; ++s) acc[s] = (f32x4){0.f, 0.f, 0.f, 0.f};

#pragma unroll
    for (int kc = 0; kc < 8; ++kc) {
        const int k0 = kc * 32 + quad * 8;
        float4 a0 = *(const float4*)(xrow + k0);
        float4 a1 = *(const float4*)(xrow + k0 + 4);
        bf16x8 af = cvt8(a0, a1);
        const short* bbase = &wfrag[((size_t)(kc * 8) * 64 + lane) * 8];
#pragma unroll
        for (int s = 0; s < 8; ++s) {
            bf16x8 bf = *(const bf16x8*)(bbase + (size_t)s * 64 * 8);
            acc[s] = __builtin_amdgcn_mfma_f32_16x16x32_bf16(af, bf, acc[s], 0, 0, 0);
        }
    }

    const int rowBase = blockIdx.x * 64 + wave * 16 + quad * 4;
#pragma unroll
    for (int reg = 0; reg < 4; ++reg) {
        const int r = rowBase + reg;
        if (r < N_NODES) {
#pragma unroll
            for (int s = 0; s < 8; ++s) {
                const int col = s * 16 + l16;
                float v = acc[s][reg] + bias[col];
                support[(size_t)r * HIDDEN + col] = f2bf(v);
            }
        }
    }
}

// ---------------------------------------------------------------------------
// Pass A: per-(block,bucket) histogram. cnt[blk*NB + b]. LDS atomics only.
// ---------------------------------------------------------------------------
__global__ __launch_bounds__(512) void bucket_count_kernel(
    const int* __restrict__ adj_row, int* __restrict__ cnt)
{
    __shared__ int lcnt[NB];
    const int tid = threadIdx.x;
    for (int i = tid; i < NB; i += 512) lcnt[i] = 0;
    __syncthreads();
    const int base = blockIdx.x * EBLOCK;
#pragma unroll
    for (int i = 0; i < EBLOCK / 512; ++i) {
        int e = base + tid + i * 512;
        if (e < N_EDGES) atomicAdd(&lcnt[adj_row[e] >> 7], 1);
    }
    __syncthreads();
    for (int b = tid; b < NB; b += 512) cnt[blockIdx.x * NB + b] = lcnt[b];
}

// ---------------------------------------------------------------------------
// Pass B: single block. For each bucket b (thread b): exclusive prefix over
// blocks (in-place on cnt), then exclusive scan of bucket totals -> bases,
// added back into cnt. bucket_base[NB] = N_EDGES.
// ---------------------------------------------------------------------------
__global__ __launch_bounds__(512) void bucket_scan_kernel(
    int* __restrict__ cnt, int* __restrict__ bucket_base)
{
    __shared__ int tot[512];
    const int b = threadIdx.x;
    int sum = 0;
    if (b < NB) {
        for (int i = 0; i < EBLOCKS; ++i) {
            int c = cnt[i * NB + b];
            cnt[i * NB + b] = sum;
            sum += c;
        }
    }
    tot[b] = (b < NB) ? sum : 0;
    __syncthreads();
    int v = tot[b];
#pragma unroll
    for (int off = 1; off < 512; off <<= 1) {
        int t = (b >= off) ? tot[b - off] : 0;
        __syncthreads();
        tot[b] += t;
        __syncthreads();
    }
    int base = tot[b] - v;   // exclusive
    if (b < NB) {
        bucket_base[b] = base;
        for (int i = 0; i < EBLOCKS; ++i) cnt[i * NB + b] += base;
    }
    if (b == 0) bucket_base[NB] = N_EDGES;
}

// ---------------------------------------------------------------------------
// Pass C: partition edges into bucket-grouped order. Block stages its 4096
// edges grouped-by-bucket in LDS, then writes bucket-contiguous runs.
// Entry: .x = (row&127)<<16 | col  (col < 50000 < 2^16), .y = val bits.
// ---------------------------------------------------------------------------
__global__ __launch_bounds__(512) void partition_kernel(
    const int* __restrict__ adj_row, const int* __restrict__ adj_col,
    const float* __restrict__ adj_val, const int* __restrict__ cnt,
    int2* __restrict__ part)
{
    __shared__ int  lcnt[512];        // scan buffer (NB<=512)
    __shared__ int  lofs[NB + 1];
    __shared__ int  lcur[NB];
    __shared__ int2 lbuf[EBLOCK];     // 32 KB

    const int tid  = threadIdx.x;
    const int base = blockIdx.x * EBLOCK;
    const int n    = min(EBLOCK, N_EDGES - base);

    int er[EBLOCK / 512], ec[EBLOCK / 512]; float ev[EBLOCK / 512];
#pragma unroll
    for (int i = 0; i < EBLOCK / 512; ++i) {
        int e = base + tid + i * 512;
        bool ok = e < N_EDGES;
        int ee = ok ? e : base;              // safe addr; masked later
        er[i] = adj_row[ee]; ec[i] = adj_col[ee]; ev[i] = adj_val[ee];
        if (!ok) er[i] = -1;
    }

    lcnt[tid] = 0;
    __syncthreads();
#pragma unroll
    for (int i = 0; i < EBLOCK / 512; ++i)
        if (er[i] >= 0) atomicAdd(&lcnt[er[i] >> 7], 1);
    __syncthreads();

    // exclusive scan of lcnt over 512
    int v = lcnt[tid];
    int run = v;
#pragma unroll
    for (int off = 1; off < 512; off <<= 1) {
        int t = (tid >= off) ? lcnt[tid - off] : 0;
        __syncthreads();
        lcnt[tid] += t;
        run = lcnt[tid];
        __syncthreads();
    }
    if (tid < NB) { lofs[tid] = run - v; lcur[tid] = run - v; }
    if (tid == 0) lofs[NB] = n;
    __syncthreads();

#pragma unroll
    for (int i = 0; i < EBLOCK / 512; ++i) {
        if (er[i] >= 0) {
            int bk = er[i] >> 7;
            int p  = atomicAdd(&lcur[bk], 1);
            lbuf[p] = make_int2(((er[i] & 127) << 16) | ec[i], __float_as_int(ev[i]));
        }
    }
    __syncthreads();

    // write out: entry j -> global cnt[blk*NB + b] + (j - lofs[b])
    const int* offrow = cnt + blockIdx.x * NB;
    for (int j = tid; j < n; j += 512) {
        int lo = 0, hi = NB;
        while (hi - lo > 1) {                 // largest b with lofs[b] <= j
            int mid = (lo + hi) >> 1;
            if (lofs[mid] <= j) lo = mid; else hi = mid;
        }
        part[offrow[lo] + (j - lofs[lo])] = lbuf[j];
    }
}

// ---------------------------------------------------------------------------
// Pass D: one block per bucket. Row-histogram + scan -> row_ptr slice; place
// edges into LDS staging in CSR order; write CSR slice coalesced.
// ---------------------------------------------------------------------------
__global__ __launch_bounds__(256) void build_csr_kernel(
    const int2* __restrict__ part, const int* __restrict__ bucket_base,
    int* __restrict__ row_ptr, int2* __restrict__ csr_cv)
{
    __shared__ int  hist[BUCKET_SZ];
    __shared__ int  sc[256];
    __shared__ int  lofs[BUCKET_SZ];
    __shared__ int  lcur[BUCKET_SZ];
    __shared__ int2 sbuf[D_CAP];      // 24 KB

    const int b     = blockIdx.x;
    const int tid   = threadIdx.x;
    const int start = bucket_base[b];
    const int n     = bucket_base[b + 1] - start;

    if (tid < BUCKET_SZ) hist[tid] = 0;
    __syncthreads();
    for (int j = tid; j < n; j += 256)
        atomicAdd(&hist[part[start + j].x >> 16], 1);
    __syncthreads();

    int v = (tid < BUCKET_SZ) ? hist[tid] : 0;
    sc[tid] = v;
    __syncthreads();
#pragma unroll
    for (int off = 1; off < 256; off <<= 1) {
        int t = (tid >= off) ? sc[tid - off] : 0;
        __syncthreads();
        sc[tid] += t;
        __syncthreads();
    }
    if (tid < BUCKET_SZ) {
        int ex = sc[tid] - v;                 // exclusive
        lofs[tid] = ex;
        lcur[tid] = ex;
        int g = b * BUCKET_SZ + tid;
        if (g < N_NODES) row_ptr[g] = start + ex;
    }
    if (b == NB - 1 && tid == 0) row_ptr[N_NODES] = N_EDGES;
    __syncthreads();

    for (int j = tid; j < n; j += 256) {
        int2 cv = part[start + j];
        int r   = cv.x >> 16;
        int2 ov = make_int2(cv.x & 0xFFFF, cv.y);
        int p   = atomicAdd(&lcur[r], 1);
        if (p < D_CAP) sbuf[p] = ov;
        else           csr_cv[start + p] = ov;   // statistically never
    }
    __syncthreads();
    int m = min(n, D_CAP);
    for (int j = tid; j < m; j += 256) csr_cv[start + j] = sbuf[j];
}

// ---------------------------------------------------------------------------
// Gather: wave-per-row; lane handles 2 features via one uint (2x bf16) load.
// ---------------------------------------------------------------------------
__global__ __launch_bounds__(256) void gather_kernel(
    const int* __restrict__ row_ptr, const int2* __restrict__ csr_cv,
    const unsigned int* __restrict__ support_u32, float* __restrict__ out)
{
    const int wave = threadIdx.x >> 6;
    const int lane = threadIdx.x & 63;
    const int r = blockIdx.x * 4 + wave;
    if (r >= N_NODES) return;

    const int s = row_ptr[r], e = row_ptr[r + 1];
    float accx = 0.f, accy = 0.f;
    int i = s;
    for (; i + 3 < e; i += 4) {
        int2 cv0 = csr_cv[i];
        int2 cv1 = csr_cv[i + 1];
        int2 cv2 = csr_cv[i + 2];
        int2 cv3 = csr_cv[i + 3];
        unsigned u0 = support_u32[(size_t)cv0.x * 64 + lane];
        unsigned u1 = support_u32[(size_t)cv1.x * 64 + lane];
        unsigned u2 = support_u32[(size_t)cv2.x * 64 + lane];
        unsigned u3 = support_u32[(size_t)cv3.x * 64 + lane];
        float v0 = __int_as_float(cv0.y), v1 = __int_as_float(cv1.y);
        float v2 = __int_as_float(cv2.y), v3 = __int_as_float(cv3.y);
        accx += v0 * __uint_as_float(u0 << 16);
        accy += v0 * __uint_as_float(u0 & 0xFFFF0000u);
        accx += v1 * __uint_as_float(u1 << 16);
        accy += v1 * __uint_as_float(u1 & 0xFFFF0000u);
        accx += v2 * __uint_as_float(u2 << 16);
        accy += v2 * __uint_as_float(u2 & 0xFFFF0000u);
        accx += v3 * __uint_as_float(u3 << 16);
        accy += v3 * __uint_as_float(u3 & 0xFFFF0000u);
    }
    for (; i < e; ++i) {
        int2 cv = csr_cv[i];
        unsigned u = support_u32[(size_t)cv.x * 64 + lane];
        float v = __int_as_float(cv.y);
        accx += v * __uint_as_float(u << 16);
        accy += v * __uint_as_float(u & 0xFFFF0000u);
    }
    *(float2*)(out + (size_t)r * HIDDEN + lane * 2) = make_float2(accx, accy);
}

extern "C" void kernel_launch(void* const* d_in, const int* in_sizes, int n_in,
                              void* d_out, int out_size, void* d_ws, size_t ws_size,
                              hipStream_t stream) {
    const float* x       = (const float*)d_in[0];
    const int*   adj_row = (const int*)d_in[1];
    const int*   adj_col = (const int*)d_in[2];
    const float* adj_val = (const float*)d_in[3];
    const float* W       = (const float*)d_in[4];
    const float* b       = (const float*)d_in[5];
    float* out = (float*)d_out;

    char* wsb = (char*)d_ws;
    const size_t off_support = 0;                                         // 12.8 MB bf16
    const size_t off_rowptr  = off_support + (size_t)N_NODES * HIDDEN * 2;
    const size_t off_csrcv   = (off_rowptr + (size_t)(N_NODES + 1) * 4 + 15) & ~(size_t)15;
    const size_t off_part    = off_csrcv + (size_t)N_EDGES * 8;           // 6.4 MB
    const size_t off_cnt     = off_part + (size_t)N_EDGES * 8;            // 6.4 MB
    const size_t off_bbase   = off_cnt + (size_t)EBLOCKS * NB * 4;        // 306 KB

    unsigned short* support = (unsigned short*)(wsb + off_support);
    int*   row_ptr = (int*)(wsb + off_rowptr);
    int2*  csr_cv  = (int2*)(wsb + off_csrcv);
    int2*  part    = (int2*)(wsb + off_part);
    int*   cnt     = (int*)(wsb + off_cnt);
    int*   bbase   = (int*)(wsb + off_bbase);

    linear_mfma_kernel<<<(N_NODES + 63) / 64, 256, 0, stream>>>(x, W, b, support);

    bucket_count_kernel<<<EBLOCKS, 512, 0, stream>>>(adj_row, cnt);
    bucket_scan_kernel<<<1, 512, 0, stream>>>(cnt, bbase);
    partition_kernel<<<EBLOCKS, 512, 0, stream>>>(
        adj_row, adj_col, adj_val, cnt, part);
    build_csr_kernel<<<NB, 256, 0, stream>>>(part, bbase, row_ptr, csr_cv);
    gather_kernel<<<(N_NODES + 3) / 4, 256, 0, stream>>>(
        row_ptr, csr_cv, (const unsigned int*)support, out);
}